// Round 2
// baseline (419.238 us; speedup 1.0000x reference)
//
#include <hip/hip_runtime.h>
#include <math.h>

#define NB 8
#define LQ 2048
#define EE 1024
#define DD 64
#define MROWS (NB * LQ) // 16384

typedef __attribute__((ext_vector_type(4))) float f32x4;
typedef __attribute__((ext_vector_type(8))) short s16x8;
typedef __attribute__((ext_vector_type(4))) short s16x4;
typedef __attribute__((ext_vector_type(4))) int i32x4;

__device__ __forceinline__ unsigned f2bf_u(float f) {
  unsigned u = __builtin_bit_cast(unsigned, f);
  u += 0x7FFFu + ((u >> 16) & 1u); // RNE
  return u >> 16;
}
__device__ __forceinline__ float bf2f(unsigned h) {
  unsigned u = h << 16;
  return __builtin_bit_cast(float, u);
}

// ---------------------------------------------------------------------------
// Kernel 1: W [1024][64] fp32 -> wt [3 tensors][hi,lo][64 d][1024 k] bf16
// ---------------------------------------------------------------------------
__global__ __launch_bounds__(256) void wsplit_kernel(
    const float* __restrict__ Wq, const float* __restrict__ Wk,
    const float* __restrict__ Wv, short* __restrict__ wt) {
  int bk = blockIdx.x; // 16 blocks of 64 k-rows
  int z = blockIdx.y;  // tensor
  const float* W = (z == 0) ? Wq : (z == 1) ? Wk : Wv;
  __shared__ float tile[64][65];
  int t = threadIdx.x;
#pragma unroll
  for (int it = 0; it < 16; ++it) {
    int kk = it * 4 + (t >> 6);
    int d = t & 63;
    tile[kk][d] = W[(size_t)(bk * 64 + kk) * 64 + d]; // coalesced
  }
  __syncthreads();
#pragma unroll
  for (int it = 0; it < 16; ++it) {
    int d = it * 4 + (t >> 6);
    int kk = t & 63;
    float f = tile[kk][d];
    unsigned h = f2bf_u(f);
    unsigned l = f2bf_u(f - bf2f(h));
    wt[((size_t)(z * 2 + 0) * 64 + d) * 1024 + bk * 64 + kk] = (short)h;
    wt[((size_t)(z * 2 + 1) * 64 + d) * 1024 + bk * 64 + kk] = (short)l;
  }
}

// ---------------------------------------------------------------------------
// Kernel 2: projection GEMM y = x @ W, split-bf16 MFMA for q,k; plain bf16
// for v. BM=64 (grid 768 -> 3 blocks/CU, LDS 36KB -> 4 blocks/CU capacity).
// Register-prefetch of next tile overlaps global latency with MFMA.
// q,k out: packed int (hi|lo<<16) [16384][64]. v out: bf16 TRANSPOSED
// [n][d][s] so attention never transposes V again.
// ---------------------------------------------------------------------------
__global__ __launch_bounds__(256, 4) void proj_kernel(
    const float* __restrict__ xq, const float* __restrict__ xk,
    const float* __restrict__ xv, const short* __restrict__ wt,
    int* __restrict__ qkp, short* __restrict__ vhp_t) {
  int z = blockIdx.y;
  const float* x = (z == 0) ? xq : (z == 1) ? xk : xv;
  const short* wthi = wt + (size_t)(z * 2 + 0) * 64 * 1024;
  const short* wtlo = wt + (size_t)(z * 2 + 1) * 64 * 1024;
  int row0 = blockIdx.x * 64;
  __shared__ short xs_hi[64][72];
  __shared__ short xs_lo[64][72];
  __shared__ short wh[64][72];
  __shared__ short wl[64][72];
  int t = threadIdx.x;
  int wv = t >> 6, lane = t & 63;
  int c = lane & 15, quad = lane >> 4;
  bool split = (z < 2);
  f32x4 acc[4] = {};
  f32x4 xr[4];
  s16x4 wrh[4], wrl[4];

  auto load_tiles = [&](int kb) {
#pragma unroll
    for (int it = 0; it < 4; ++it) {
      int flat4 = it * 256 + t;
      int r = flat4 >> 4, c4 = (flat4 & 15) * 4;
      xr[it] = *(const f32x4*)&x[(size_t)(row0 + r) * 1024 + kb * 64 + c4];
      wrh[it] = *(const s16x4*)&wthi[(size_t)r * 1024 + kb * 64 + c4];
      if (split)
        wrl[it] = *(const s16x4*)&wtlo[(size_t)r * 1024 + kb * 64 + c4];
    }
  };

  load_tiles(0);
  for (int kb = 0; kb < 16; ++kb) {
    // convert + store staged registers to LDS
#pragma unroll
    for (int it = 0; it < 4; ++it) {
      int flat4 = it * 256 + t;
      int r = flat4 >> 4, c4 = (flat4 & 15) * 4;
      s16x4 h, l;
#pragma unroll
      for (int j = 0; j < 4; ++j) {
        unsigned hh = f2bf_u(xr[it][j]);
        h[j] = (short)hh;
        l[j] = (short)f2bf_u(xr[it][j] - bf2f(hh));
      }
      *(s16x4*)&xs_hi[r][c4] = h;
      if (split) *(s16x4*)&xs_lo[r][c4] = l;
      *(s16x4*)&wh[r][c4] = wrh[it];
      if (split) *(s16x4*)&wl[r][c4] = wrl[it];
    }
    __syncthreads();
    if (kb < 15) load_tiles(kb + 1); // overlaps MFMA below
#pragma unroll
    for (int kc = 0; kc < 2; ++kc) {
      s16x8 ah = *(const s16x8*)&xs_hi[wv * 16 + c][kc * 32 + quad * 8];
      s16x8 al = {};
      if (split) al = *(const s16x8*)&xs_lo[wv * 16 + c][kc * 32 + quad * 8];
#pragma unroll
      for (int cs = 0; cs < 4; ++cs) {
        s16x8 bh = *(const s16x8*)&wh[cs * 16 + c][kc * 32 + quad * 8];
        acc[cs] = __builtin_amdgcn_mfma_f32_16x16x32_bf16(ah, bh, acc[cs], 0, 0, 0);
        if (split) {
          s16x8 bl = *(const s16x8*)&wl[cs * 16 + c][kc * 32 + quad * 8];
          acc[cs] = __builtin_amdgcn_mfma_f32_16x16x32_bf16(ah, bl, acc[cs], 0, 0, 0);
          acc[cs] = __builtin_amdgcn_mfma_f32_16x16x32_bf16(al, bh, acc[cs], 0, 0, 0);
        }
      }
    }
    __syncthreads();
  }
  // epilogue: C layout row = quad*4+r, col = lane&15
  if (split) {
#pragma unroll
    for (int cs = 0; cs < 4; ++cs)
#pragma unroll
      for (int r = 0; r < 4; ++r) {
        int row = row0 + wv * 16 + quad * 4 + r;
        int col = cs * 16 + c;
        float val = acc[cs][r];
        unsigned h = f2bf_u(val);
        unsigned l = f2bf_u(val - bf2f(h));
        qkp[(size_t)z * MROWS * 64 + (size_t)row * 64 + col] = (int)(h | (l << 16));
      }
  } else {
    // bounce through LDS (loop ended on a barrier; xs_hi free) to store V
    // transposed with coalesced global writes
#pragma unroll
    for (int cs = 0; cs < 4; ++cs)
#pragma unroll
      for (int r = 0; r < 4; ++r)
        xs_hi[wv * 16 + quad * 4 + r][cs * 16 + c] = (short)f2bf_u(acc[cs][r]);
    __syncthreads();
    int n = row0 >> 11;
    int s0l = row0 & 2047;
#pragma unroll
    for (int it = 0; it < 4; ++it) {
      int flat4 = it * 256 + t;
      int d = flat4 >> 4, s4 = (flat4 & 15) * 4;
      s16x4 vv;
#pragma unroll
      for (int j = 0; j < 4; ++j) vv[j] = xs_hi[s4 + j][d];
      *(s16x4*)&vhp_t[((size_t)n * 64 + d) * 2048 + s0l + s4] = vv;
    }
  }
}

// ---------------------------------------------------------------------------
// Kernel 3: causal flash attention. 32-row q-tiles, 128 threads (2 waves x 16
// rows), grid (n=8, y=64) = 512 blocks, all co-resident (LDS 31.5KB -> 5/CU).
// Complementary pairing qt2 = y<32 ? y : 95-y makes per-CU work ~constant.
// ---------------------------------------------------------------------------
__global__ __launch_bounds__(128) void attn_kernel(
    const int* __restrict__ qkp, const short* __restrict__ vhp_t,
    float* __restrict__ outp) {
  int n = blockIdx.x; // 0..7
  int y = blockIdx.y; // 0..63
  int qt2 = (y < 32) ? y : (95 - y);
  int qr0 = qt2 * 32;
  int nk = qt2 / 2 + 1; // number of 64-wide k tiles
  const int* qp = qkp;
  const int* kp = qkp + (size_t)MROWS * 64;
  __shared__ short ksh[64][72];
  __shared__ short ksl[64][72];
  __shared__ short vT[64][72];    // V transposed [d][s] (already in vhp_t)
  __shared__ short pS[2][16][72]; // per-wave P transpose buffer
  int t = threadIdx.x;
  int wv = t >> 6, lane = t & 63;
  int c = lane & 15, quad = lane >> 4;
  // Q A-fragments (rows qr0 + wv*16 + c), hi/lo unpack from packed int
  s16x8 qfh[2], qfl[2];
  size_t qbase = ((size_t)n * LQ + qr0 + wv * 16 + c) * 64;
#pragma unroll
  for (int kc = 0; kc < 2; ++kc) {
    i32x4 v0 = *(const i32x4*)&qp[qbase + kc * 32 + quad * 8];
    i32x4 v1 = *(const i32x4*)&qp[qbase + kc * 32 + quad * 8 + 4];
#pragma unroll
    for (int j = 0; j < 4; ++j) {
      qfh[kc][j] = (short)(v0[j] & 0xffff);
      qfl[kc][j] = (short)(((unsigned)v0[j]) >> 16);
      qfh[kc][4 + j] = (short)(v1[j] & 0xffff);
      qfl[kc][4 + j] = (short)(((unsigned)v1[j]) >> 16);
    }
  }
  f32x4 o[4] = {};
  float m_r[4], l_r[4];
#pragma unroll
  for (int r = 0; r < 4; ++r) { m_r[r] = -INFINITY; l_r[r] = 0.0f; }

  for (int kt = 0; kt < nk; ++kt) {
    int s0 = kt * 64;
    // stage K (unpack split) — 1024 i32x4 over 128 threads
#pragma unroll
    for (int it = 0; it < 8; ++it) {
      int flat4 = it * 128 + t;
      int s = flat4 >> 4, d4 = (flat4 & 15) * 4;
      i32x4 kv = *(const i32x4*)&kp[((size_t)n * LQ + s0 + s) * 64 + d4];
      s16x4 h, l;
#pragma unroll
      for (int j = 0; j < 4; ++j) {
        h[j] = (short)(kv[j] & 0xffff);
        l[j] = (short)(((unsigned)kv[j]) >> 16);
      }
      *(s16x4*)&ksh[s][d4] = h;
      *(s16x4*)&ksl[s][d4] = l;
    }
    // stage V^T rows (contiguous copies, no transpose needed)
#pragma unroll
    for (int it = 0; it < 8; ++it) {
      int flat4 = it * 128 + t;
      int d = flat4 >> 4, s4 = (flat4 & 15) * 4;
      *(s16x4*)&vT[d][s4] =
          *(const s16x4*)&vhp_t[((size_t)n * 64 + d) * 2048 + s0 + s4];
    }
    __syncthreads();
    // S = Q K^T (split-bf16: hh + hl + lh)
    f32x4 sa[4] = {};
#pragma unroll
    for (int ct = 0; ct < 4; ++ct) {
#pragma unroll
      for (int kc = 0; kc < 2; ++kc) {
        s16x8 bh = *(const s16x8*)&ksh[ct * 16 + c][kc * 32 + quad * 8];
        s16x8 bl = *(const s16x8*)&ksl[ct * 16 + c][kc * 32 + quad * 8];
        sa[ct] = __builtin_amdgcn_mfma_f32_16x16x32_bf16(qfh[kc], bh, sa[ct], 0, 0, 0);
        sa[ct] = __builtin_amdgcn_mfma_f32_16x16x32_bf16(qfh[kc], bl, sa[ct], 0, 0, 0);
        sa[ct] = __builtin_amdgcn_mfma_f32_16x16x32_bf16(qfl[kc], bh, sa[ct], 0, 0, 0);
      }
    }
    // scale (faithful bug: *sqrt(D)=8) + causal mask on last tile
    float sv[4][4];
    bool diag = (kt == nk - 1);
#pragma unroll
    for (int ct = 0; ct < 4; ++ct)
#pragma unroll
      for (int r = 0; r < 4; ++r) {
        float xsc = sa[ct][r] * 8.0f;
        if (diag) {
          int sg = s0 + ct * 16 + c;
          int qg = qr0 + wv * 16 + quad * 4 + r;
          if (sg > qg) xsc = -INFINITY;
        }
        sv[ct][r] = xsc;
      }
    // online softmax, per C-layout row (quad*4+r), reduce across 16 lanes
    float alpha[4];
#pragma unroll
    for (int r = 0; r < 4; ++r) {
      float mx = fmaxf(fmaxf(sv[0][r], sv[1][r]), fmaxf(sv[2][r], sv[3][r]));
#pragma unroll
      for (int off = 1; off < 16; off <<= 1) mx = fmaxf(mx, __shfl_xor(mx, off, 64));
      float mnew = fmaxf(m_r[r], mx);
      alpha[r] = exp2f((m_r[r] - mnew) * 1.44269504088896f);
      m_r[r] = mnew;
      float rs = 0.0f;
#pragma unroll
      for (int ct = 0; ct < 4; ++ct) {
        float p = exp2f((sv[ct][r] - mnew) * 1.44269504088896f);
        sv[ct][r] = p;
        rs += p;
      }
#pragma unroll
      for (int off = 1; off < 16; off <<= 1) rs += __shfl_xor(rs, off, 64);
      l_r[r] = l_r[r] * alpha[r] + rs;
    }
#pragma unroll
    for (int dt = 0; dt < 4; ++dt)
#pragma unroll
      for (int r = 0; r < 4; ++r) o[dt][r] *= alpha[r];
    // P: C-layout -> LDS -> A-layout (per-wave region, intra-wave ordering)
#pragma unroll
    for (int ct = 0; ct < 4; ++ct)
#pragma unroll
      for (int r = 0; r < 4; ++r)
        pS[wv][quad * 4 + r][ct * 16 + c] = (short)f2bf_u(sv[ct][r]);
    s16x8 pa[2];
#pragma unroll
    for (int kc2 = 0; kc2 < 2; ++kc2)
      pa[kc2] = *(const s16x8*)&pS[wv][c][kc2 * 32 + quad * 8];
    // O += P V
#pragma unroll
    for (int dt = 0; dt < 4; ++dt) {
#pragma unroll
      for (int kc2 = 0; kc2 < 2; ++kc2) {
        s16x4 v0 = *(const s16x4*)&vT[dt * 16 + c][kc2 * 32 + quad * 8];
        s16x4 v1 = *(const s16x4*)&vT[dt * 16 + c][kc2 * 32 + quad * 8 + 4];
        s16x8 vb;
#pragma unroll
        for (int j = 0; j < 4; ++j) { vb[j] = v0[j]; vb[4 + j] = v1[j]; }
        o[dt] = __builtin_amdgcn_mfma_f32_16x16x32_bf16(pa[kc2], vb, o[dt], 0, 0, 0);
      }
    }
    __syncthreads();
  }
  // epilogue: normalize and store fp32
#pragma unroll
  for (int dt = 0; dt < 4; ++dt)
#pragma unroll
    for (int r = 0; r < 4; ++r) {
      int row = qr0 + wv * 16 + quad * 4 + r;
      outp[((size_t)n * LQ + row) * 64 + dt * 16 + c] = o[dt][r] / l_r[r];
    }
}

// ---------------------------------------------------------------------------
extern "C" void kernel_launch(void* const* d_in, const int* in_sizes, int n_in,
                              void* d_out, int out_size, void* d_ws, size_t ws_size,
                              hipStream_t stream) {
  const float* q = (const float*)d_in[0];
  const float* k = (const float*)d_in[1];
  const float* v = (const float*)d_in[2];
  const float* Wq = (const float*)d_in[3];
  const float* Wk = (const float*)d_in[4];
  const float* Wv = (const float*)d_in[5];
  // d_in[6] = attn_mask: ignored (known causal triu mask)
  float* out = (float*)d_out;

  char* ws = (char*)d_ws;
  // ws layout: wt (3*2*64*1024 shorts = 786432 B) | qkp (2*16384*64 ints =
  // 8388608 B) | vhp_t (8*64*2048 shorts = 2097152 B)  -> ~10.75 MB total
  short* wt = (short*)ws;
  int* qkp = (int*)(ws + 786432);
  short* vhp_t = (short*)(ws + 786432 + 8388608);

  wsplit_kernel<<<dim3(16, 3), 256, 0, stream>>>(Wq, Wk, Wv, wt);
  proj_kernel<<<dim3(256, 3), 256, 0, stream>>>(q, k, v, wt, qkp, vhp_t);
  attn_kernel<<<dim3(8, 64), 128, 0, stream>>>(qkp, vhp_t, out);
}

// Round 4
// 363.788 us; speedup vs baseline: 1.1524x; 1.1524x over previous
//
#include <hip/hip_runtime.h>
#include <math.h>

#define NB 8
#define LQ 2048
#define EE 1024
#define DD 64
#define MROWS (NB * LQ) // 16384
#define L2E 1.44269504088896f

typedef __attribute__((ext_vector_type(4))) float f32x4;
typedef __attribute__((ext_vector_type(8))) short s16x8;
typedef __attribute__((ext_vector_type(4))) short s16x4;
typedef __attribute__((ext_vector_type(4))) int i32x4;

__device__ __forceinline__ unsigned f2bf_u(float f) {
  unsigned u = __builtin_bit_cast(unsigned, f);
  u += 0x7FFFu + ((u >> 16) & 1u); // RNE
  return u >> 16;
}
__device__ __forceinline__ float bf2f(unsigned h) {
  unsigned u = h << 16;
  return __builtin_bit_cast(float, u);
}

// ---------------------------------------------------------------------------
// Kernel 1: W [1024][64] fp32 -> wt [3 tensors][hi,lo][64 d][1024 k] bf16
// ---------------------------------------------------------------------------
__global__ __launch_bounds__(256) void wsplit_kernel(
    const float* __restrict__ Wq, const float* __restrict__ Wk,
    const float* __restrict__ Wv, short* __restrict__ wt) {
  int bk = blockIdx.x;
  int z = blockIdx.y;
  const float* W = (z == 0) ? Wq : (z == 1) ? Wk : Wv;
  __shared__ float tile[64][65];
  int t = threadIdx.x;
#pragma unroll
  for (int it = 0; it < 16; ++it) {
    int kk = it * 4 + (t >> 6);
    int d = t & 63;
    tile[kk][d] = W[(size_t)(bk * 64 + kk) * 64 + d];
  }
  __syncthreads();
#pragma unroll
  for (int it = 0; it < 16; ++it) {
    int d = it * 4 + (t >> 6);
    int kk = t & 63;
    float f = tile[kk][d];
    unsigned h = f2bf_u(f);
    unsigned l = f2bf_u(f - bf2f(h));
    wt[((size_t)(z * 2 + 0) * 64 + d) * 1024 + bk * 64 + kk] = (short)h;
    wt[((size_t)(z * 2 + 1) * 64 + d) * 1024 + bk * 64 + kk] = (short)l;
  }
}

// ---------------------------------------------------------------------------
// Kernel 2: barrier-free projection. Each wave owns 16 rows; A-frags are
// loaded fp32 direct from global and split in-register; W B-frags stream from
// L2. Software-pipelined x loads. q,k -> packed (hi|lo<<16) int; v -> bf16
// transposed [n][d][s] via per-wave LDS bounce.
// ---------------------------------------------------------------------------
__global__ __launch_bounds__(256, 3) void proj_kernel(
    const float* __restrict__ xq, const float* __restrict__ xk,
    const float* __restrict__ xv, const short* __restrict__ wt,
    int* __restrict__ qkp, short* __restrict__ vhp_t) {
  __shared__ short vls[4][16][68];
  int t = threadIdx.x;
  int wv = t >> 6, lane = t & 63;
  int c = lane & 15, quad = lane >> 4;
  int w = blockIdx.x * 4 + wv; // 0..3071
  int z = w >> 10;             // tensor
  int rowg = w & 1023;         // 16-row group
  const float* x = (z == 0) ? xq : (z == 1) ? xk : xv;
  const short* wthi = wt + (size_t)(z * 2) * 64 * 1024;
  const short* wtlo = wthi + 64 * 1024;
  bool split = (z < 2);
  const float* xr = x + (size_t)(rowg * 16 + c) * 1024; // this lane's A row

  f32x4 acc[4] = {};
  f32x4 cur[2][2], nxt[2][2]; // [kc][half]
#pragma unroll
  for (int kc = 0; kc < 2; ++kc) {
    cur[kc][0] = *(const f32x4*)&xr[kc * 32 + quad * 8];
    cur[kc][1] = *(const f32x4*)&xr[kc * 32 + quad * 8 + 4];
  }
  for (int kb = 0; kb < 16; ++kb) {
    if (kb < 15) {
#pragma unroll
      for (int kc = 0; kc < 2; ++kc) {
        nxt[kc][0] = *(const f32x4*)&xr[(kb + 1) * 64 + kc * 32 + quad * 8];
        nxt[kc][1] = *(const f32x4*)&xr[(kb + 1) * 64 + kc * 32 + quad * 8 + 4];
      }
    }
    // split-convert current x into A-frags
    s16x8 ah[2], al[2];
#pragma unroll
    for (int kc = 0; kc < 2; ++kc)
#pragma unroll
      for (int h = 0; h < 2; ++h)
#pragma unroll
        for (int j = 0; j < 4; ++j) {
          float f = cur[kc][h][j];
          unsigned hh = f2bf_u(f);
          ah[kc][h * 4 + j] = (short)hh;
          al[kc][h * 4 + j] = (short)f2bf_u(f - bf2f(hh));
        }
#pragma unroll
    for (int cs = 0; cs < 4; ++cs) {
      const short* bp = wthi + (size_t)(cs * 16 + c) * 1024 + kb * 64 + quad * 8;
      s16x8 bh0 = *(const s16x8*)bp;
      s16x8 bh1 = *(const s16x8*)(bp + 32);
      acc[cs] = __builtin_amdgcn_mfma_f32_16x16x32_bf16(ah[0], bh0, acc[cs], 0, 0, 0);
      acc[cs] = __builtin_amdgcn_mfma_f32_16x16x32_bf16(ah[1], bh1, acc[cs], 0, 0, 0);
      if (split) {
        const short* bpl = wtlo + (size_t)(cs * 16 + c) * 1024 + kb * 64 + quad * 8;
        s16x8 bl0 = *(const s16x8*)bpl;
        s16x8 bl1 = *(const s16x8*)(bpl + 32);
        acc[cs] = __builtin_amdgcn_mfma_f32_16x16x32_bf16(ah[0], bl0, acc[cs], 0, 0, 0);
        acc[cs] = __builtin_amdgcn_mfma_f32_16x16x32_bf16(al[0], bh0, acc[cs], 0, 0, 0);
        acc[cs] = __builtin_amdgcn_mfma_f32_16x16x32_bf16(ah[1], bl1, acc[cs], 0, 0, 0);
        acc[cs] = __builtin_amdgcn_mfma_f32_16x16x32_bf16(al[1], bh1, acc[cs], 0, 0, 0);
      }
    }
#pragma unroll
    for (int kc = 0; kc < 2; ++kc)
#pragma unroll
      for (int h = 0; h < 2; ++h) cur[kc][h] = nxt[kc][h];
  }
  // epilogue: C layout row = quad*4+r, col = cs*16+c
  if (split) {
#pragma unroll
    for (int cs = 0; cs < 4; ++cs)
#pragma unroll
      for (int r = 0; r < 4; ++r) {
        int row = rowg * 16 + quad * 4 + r;
        float val = acc[cs][r];
        unsigned h = f2bf_u(val);
        unsigned l = f2bf_u(val - bf2f(h));
        qkp[(size_t)z * MROWS * 64 + (size_t)row * 64 + cs * 16 + c] =
            (int)(h | (l << 16));
      }
  } else {
    // per-wave LDS transpose bounce (intra-wave: no barrier needed)
#pragma unroll
    for (int cs = 0; cs < 4; ++cs)
#pragma unroll
      for (int r = 0; r < 4; ++r)
        vls[wv][quad * 4 + r][cs * 16 + c] = (short)f2bf_u(acc[cs][r]);
    int n = rowg >> 7;
    int sb = (rowg * 16) & 2047;
    s16x8 p0, p1;
#pragma unroll
    for (int j = 0; j < 8; ++j) {
      p0[j] = vls[wv][j][lane];
      p1[j] = vls[wv][8 + j][lane];
    }
    *(s16x8*)&vhp_t[((size_t)n * 64 + lane) * 2048 + sb] = p0;
    *(s16x8*)&vhp_t[((size_t)n * 64 + lane) * 2048 + sb + 8] = p1;
  }
}

// ---------------------------------------------------------------------------
// Kernel 3: barrier-free causal flash attention with split-K partials.
// Each wave owns 16 q-rows and one k-chunk; K/V/Q fragments loaded direct
// from global (L2-resident workspace). Row-sum l accumulated via MFMA with
// an all-ones B operand. Writes partial (o, m, l); combine_kernel merges.
// ---------------------------------------------------------------------------
__global__ __launch_bounds__(256, 3) void attn_kernel(
    const int* __restrict__ qkp, const short* __restrict__ vhp_t,
    float* __restrict__ po, float* __restrict__ pm, float* __restrict__ pl,
    int S) {
  __shared__ short pS[4][16][72];
  int t = threadIdx.x;
  int wv = t >> 6, lane = t & 63;
  int c = lane & 15, quad = lane >> 4;
  int w = blockIdx.x * 4 + wv;
  int qg = w & 1023;   // absolute 16-row group (includes batch)
  int split = w >> 10; // chunk id
  int n = qg >> 7;
  int qgl = qg & 127;  // batch-LOCAL 16-row group
  int nk = (qgl >> 2) + 1; // 64-wide k tiles in causal range
  int dk = qgl >> 2;       // diagonal tile index
  int k0 = (split * nk) / S, k1 = ((split + 1) * nk) / S;
  const int* qp = qkp;
  const int* kp = qkp + (size_t)MROWS * 64;

  // Q A-frags, hi/lo unpack (row = qg*16 + c)
  s16x8 qfh[2], qfl[2];
  size_t qbase = (size_t)(qg * 16 + c) * 64;
#pragma unroll
  for (int kc = 0; kc < 2; ++kc) {
    i32x4 v0 = *(const i32x4*)&qp[qbase + kc * 32 + quad * 8];
    i32x4 v1 = *(const i32x4*)&qp[qbase + kc * 32 + quad * 8 + 4];
#pragma unroll
    for (int j = 0; j < 4; ++j) {
      qfh[kc][j] = (short)(v0[j] & 0xffff);
      qfl[kc][j] = (short)(((unsigned)v0[j]) >> 16);
      qfh[kc][4 + j] = (short)(v1[j] & 0xffff);
      qfl[kc][4 + j] = (short)(((unsigned)v1[j]) >> 16);
    }
  }
  s16x8 ones;
#pragma unroll
  for (int j = 0; j < 8; ++j) ones[j] = (short)0x3F80; // bf16 1.0
  f32x4 o[4] = {};
  f32x4 lsum = {};
  float m_r[4];
#pragma unroll
  for (int r = 0; r < 4; ++r) m_r[r] = -INFINITY;

  for (int kt = k0; kt < k1; ++kt) {
    int s0 = kt * 64;
    // V B-frags direct from global (prefetch early, used after softmax)
    s16x8 vf[4][2];
#pragma unroll
    for (int dt = 0; dt < 4; ++dt)
#pragma unroll
      for (int kc2 = 0; kc2 < 2; ++kc2)
        vf[dt][kc2] = *(const s16x8*)&vhp_t[((size_t)n * 64 + dt * 16 + c) * 2048 +
                                            s0 + kc2 * 32 + quad * 8];
    // S = Q K^T, K B-frags direct from global, split-bf16 (hh+hl+lh)
    f32x4 sa[4] = {};
#pragma unroll
    for (int ct = 0; ct < 4; ++ct) {
      const int* krow = &kp[((size_t)n * 2048 + s0 + ct * 16 + c) * 64];
#pragma unroll
      for (int kc = 0; kc < 2; ++kc) {
        i32x4 p0 = *(const i32x4*)&krow[kc * 32 + quad * 8];
        i32x4 p1 = *(const i32x4*)&krow[kc * 32 + quad * 8 + 4];
        s16x8 bh, bl;
#pragma unroll
        for (int j = 0; j < 4; ++j) {
          bh[j] = (short)(p0[j] & 0xffff);
          bl[j] = (short)(((unsigned)p0[j]) >> 16);
          bh[4 + j] = (short)(p1[j] & 0xffff);
          bl[4 + j] = (short)(((unsigned)p1[j]) >> 16);
        }
        sa[ct] = __builtin_amdgcn_mfma_f32_16x16x32_bf16(qfh[kc], bh, sa[ct], 0, 0, 0);
        sa[ct] = __builtin_amdgcn_mfma_f32_16x16x32_bf16(qfh[kc], bl, sa[ct], 0, 0, 0);
        sa[ct] = __builtin_amdgcn_mfma_f32_16x16x32_bf16(qfl[kc], bh, sa[ct], 0, 0, 0);
      }
    }
    // scale (faithful bug: *sqrt(D)=8) + causal mask on diagonal tile.
    // BUGFIX (round 3): compare batch-LOCAL q row (qgl), not global (qg) —
    // global q row >= 2048 for n>=1 made the mask a no-op on 7/8 batches.
    float sv[4][4];
    bool diag = (kt == dk);
#pragma unroll
    for (int ct = 0; ct < 4; ++ct)
#pragma unroll
      for (int r = 0; r < 4; ++r) {
        float xsc = sa[ct][r] * 8.0f;
        if (diag) {
          int sg = s0 + ct * 16 + c;
          int qgr = qgl * 16 + quad * 4 + r;
          if (sg > qgr) xsc = -INFINITY;
        }
        sv[ct][r] = xsc;
      }
    // online softmax: max reduction only (l comes from MFMA below)
    float alpha[4];
#pragma unroll
    for (int r = 0; r < 4; ++r) {
      float mx = fmaxf(fmaxf(sv[0][r], sv[1][r]), fmaxf(sv[2][r], sv[3][r]));
#pragma unroll
      for (int off = 1; off < 16; off <<= 1) mx = fmaxf(mx, __shfl_xor(mx, off, 64));
      float mnew = fmaxf(m_r[r], mx);
      alpha[r] = exp2f((m_r[r] - mnew) * L2E);
      m_r[r] = mnew;
#pragma unroll
      for (int ct = 0; ct < 4; ++ct)
        sv[ct][r] = exp2f((sv[ct][r] - mnew) * L2E);
    }
#pragma unroll
    for (int dt = 0; dt < 4; ++dt)
#pragma unroll
      for (int r = 0; r < 4; ++r) o[dt][r] *= alpha[r];
#pragma unroll
    for (int r = 0; r < 4; ++r) lsum[r] *= alpha[r];
    // P: C-layout -> per-wave LDS -> A-layout (intra-wave, no barrier)
#pragma unroll
    for (int ct = 0; ct < 4; ++ct)
#pragma unroll
      for (int r = 0; r < 4; ++r)
        pS[wv][quad * 4 + r][ct * 16 + c] = (short)f2bf_u(sv[ct][r]);
    s16x8 pa[2];
#pragma unroll
    for (int kc2 = 0; kc2 < 2; ++kc2)
      pa[kc2] = *(const s16x8*)&pS[wv][c][kc2 * 32 + quad * 8];
    // l += row-sum(P) via ones-MFMA; O += P V
    lsum = __builtin_amdgcn_mfma_f32_16x16x32_bf16(pa[0], ones, lsum, 0, 0, 0);
    lsum = __builtin_amdgcn_mfma_f32_16x16x32_bf16(pa[1], ones, lsum, 0, 0, 0);
#pragma unroll
    for (int dt = 0; dt < 4; ++dt) {
      o[dt] = __builtin_amdgcn_mfma_f32_16x16x32_bf16(pa[0], vf[dt][0], o[dt], 0, 0, 0);
      o[dt] = __builtin_amdgcn_mfma_f32_16x16x32_bf16(pa[1], vf[dt][1], o[dt], 0, 0, 0);
    }
  }
  // store partials (empty chunks store zeros / -inf)
  int rb = qg * 16 + quad * 4;
#pragma unroll
  for (int dt = 0; dt < 4; ++dt)
#pragma unroll
    for (int r = 0; r < 4; ++r)
      po[((size_t)split * MROWS + rb + r) * 64 + dt * 16 + c] = o[dt][r];
  if (c == 0) {
#pragma unroll
    for (int r = 0; r < 4; ++r) {
      pm[(size_t)split * MROWS + rb + r] = m_r[r];
      pl[(size_t)split * MROWS + rb + r] = lsum[r];
    }
  }
}

// ---------------------------------------------------------------------------
// Kernel 4: merge split-K partials. 262144 threads, one f32x4 each.
// ---------------------------------------------------------------------------
__global__ __launch_bounds__(256) void combine_kernel(
    const float* __restrict__ po, const float* __restrict__ pm,
    const float* __restrict__ pl, float* __restrict__ outp, int S) {
  int id = blockIdx.x * 256 + threadIdx.x;
  int row = id >> 4;
  int c4 = (id & 15) * 4;
  float M = -INFINITY;
  for (int s = 0; s < S; ++s) M = fmaxf(M, pm[(size_t)s * MROWS + row]);
  float den = 0.0f;
  f32x4 acc = {};
  for (int s = 0; s < S; ++s) {
    float wgt = exp2f((pm[(size_t)s * MROWS + row] - M) * L2E);
    den += pl[(size_t)s * MROWS + row] * wgt;
    f32x4 pv = *(const f32x4*)&po[((size_t)s * MROWS + row) * 64 + c4];
#pragma unroll
    for (int j = 0; j < 4; ++j) acc[j] += pv[j] * wgt;
  }
  f32x4 res;
#pragma unroll
  for (int j = 0; j < 4; ++j) res[j] = acc[j] / den;
  *(f32x4*)&outp[(size_t)row * 64 + c4] = res;
}

// ---------------------------------------------------------------------------
extern "C" void kernel_launch(void* const* d_in, const int* in_sizes, int n_in,
                              void* d_out, int out_size, void* d_ws, size_t ws_size,
                              hipStream_t stream) {
  const float* q = (const float*)d_in[0];
  const float* k = (const float*)d_in[1];
  const float* v = (const float*)d_in[2];
  const float* Wq = (const float*)d_in[3];
  const float* Wk = (const float*)d_in[4];
  const float* Wv = (const float*)d_in[5];
  float* out = (float*)d_out;

  char* ws = (char*)d_ws;
  // wt: 786432 B | qkp: 8388608 B | vhp_t: 2097152 B | po/pm/pl per split
  size_t base = 786432 + 8388608 + 2097152; // 11272192
  size_t po_sz = (size_t)MROWS * 64 * 4;    // 4 MiB per split
  size_t ml_sz = (size_t)MROWS * 4;         // 64 KiB per split
  size_t per_split = po_sz + 2 * ml_sz;
  int S = 1;
  if (ws_size >= base + 4 * per_split) S = 4;
  else if (ws_size >= base + 2 * per_split) S = 2;

  short* wt = (short*)ws;
  int* qkp = (int*)(ws + 786432);
  short* vhp_t = (short*)(ws + 786432 + 8388608);
  float* po = (float*)(ws + base);
  float* pm = (float*)(ws + base + (size_t)S * po_sz);
  float* pl = (float*)(ws + base + (size_t)S * po_sz + (size_t)S * ml_sz);

  wsplit_kernel<<<dim3(16, 3), 256, 0, stream>>>(Wq, Wk, Wv, wt);
  proj_kernel<<<dim3(768), 256, 0, stream>>>(q, k, v, wt, qkp, vhp_t);
  attn_kernel<<<dim3(256 * S), 256, 0, stream>>>(qkp, vhp_t, po, pm, pl, S);
  combine_kernel<<<dim3(1024), 256, 0, stream>>>(po, pm, pl, out, S);
}

// Round 5
// 329.065 us; speedup vs baseline: 1.2740x; 1.1055x over previous
//
#include <hip/hip_runtime.h>
#include <math.h>

#define NB 8
#define LQ 2048
#define EE 1024
#define DD 64
#define MROWS (NB * LQ) // 16384
#define L2E 1.44269504088896f

typedef __attribute__((ext_vector_type(4))) float f32x4;
typedef __attribute__((ext_vector_type(8))) short s16x8;
typedef __attribute__((ext_vector_type(4))) short s16x4;
typedef __attribute__((ext_vector_type(4))) int i32x4;

__device__ __forceinline__ unsigned f2bf_u(float f) {
  unsigned u = __builtin_bit_cast(unsigned, f);
  u += 0x7FFFu + ((u >> 16) & 1u); // RNE
  return u >> 16;
}
__device__ __forceinline__ float bf2f(unsigned h) {
  unsigned u = h << 16;
  return __builtin_bit_cast(float, u);
}
// async global->LDS, 16B per lane; lds dest must be uniform-base + lane*16
__device__ __forceinline__ void gl_lds16(const void* g, void* l) {
  __builtin_amdgcn_global_load_lds(
      (const __attribute__((address_space(1))) unsigned int*)g,
      (__attribute__((address_space(3))) unsigned int*)l, 16, 0, 0);
}

// ---------------------------------------------------------------------------
// Kernel 1: W [1024][64] fp32 -> wsz: per (z, kb, hi/lo) an 8KB tile laid out
// exactly as proj's LDS image: short idx = d*64 + ((kk>>3) ^ (d&7))*8 + (kk&7)
// (XOR swizzle baked in so global_load_lds staging yields bank-spread reads).
// ---------------------------------------------------------------------------
__global__ __launch_bounds__(256) void wsplit_kernel(
    const float* __restrict__ Wq, const float* __restrict__ Wk,
    const float* __restrict__ Wv, short* __restrict__ wsz) {
  int bk = blockIdx.x; // k-block (kb), 16 of 64 rows
  int z = blockIdx.y;  // tensor
  const float* W = (z == 0) ? Wq : (z == 1) ? Wk : Wv;
  __shared__ float tile[64][65];
  int t = threadIdx.x;
#pragma unroll
  for (int it = 0; it < 16; ++it) {
    int kk = it * 4 + (t >> 6);
    int d = t & 63;
    tile[kk][d] = W[(size_t)(bk * 64 + kk) * 64 + d]; // coalesced
  }
  __syncthreads();
  size_t tb = (size_t)(z * 16 + bk) * 2 * 4096;
#pragma unroll
  for (int it = 0; it < 16; ++it) {
    int d = it * 4 + (t >> 6);
    int kk = t & 63;
    float f = tile[kk][d];
    unsigned h = f2bf_u(f);
    unsigned l = f2bf_u(f - bf2f(h));
    int idx = d * 64 + (((kk >> 3) ^ (d & 7)) * 8) + (kk & 7);
    wsz[tb + idx] = (short)h;
    wsz[tb + 4096 + idx] = (short)l;
  }
}

// ---------------------------------------------------------------------------
// Kernel 2: projection GEMM, m97-style: global_load_lds width-16 staging,
// BM=64 BK=64, 2-barrier K-loop, grid (256,3) = 768 blocks -> 3 blocks/CU.
// x tile staged with per-lane global-address XOR swizzle (16B chunks permuted
// within each 256B row -> coalescing preserved, ds_read_b128 bank-spread).
// W tiles staged as straight copies (swizzle pre-baked by wsplit).
// q,k -> packed (hi|lo<<16); v -> bf16 transposed [n][d][s].
// ---------------------------------------------------------------------------
__global__ __launch_bounds__(256) void proj_kernel(
    const float* __restrict__ xq, const float* __restrict__ xk,
    const float* __restrict__ xv, const short* __restrict__ wsz,
    int* __restrict__ qkp, short* __restrict__ vhp_t) {
  int z = blockIdx.y;
  const float* x = (z == 0) ? xq : (z == 1) ? xk : xv;
  bool split = (z < 2);
  int row0 = blockIdx.x * 64;
  __shared__ float xs[64 * 64];  // 16 KB, swizzled image
  __shared__ short whs[64 * 64]; // 8 KB
  __shared__ short wls[64 * 64]; // 8 KB
  __shared__ short pv[4][16][68];
  int t = threadIdx.x;
  int wv = t >> 6, lane = t & 63;
  int c = lane & 15, quad = lane >> 4;
  f32x4 acc[4] = {};

  for (int kb = 0; kb < 16; ++kb) {
    // --- stage x (4 insts/thread): LDS pos (m, p) <- global group g(m,p) ---
#pragma unroll
    for (int it = 0; it < 4; ++it) {
      int m = it * 16 + (t >> 4);
      int p = t & 15;
      int g = (p & 8) | ((p ^ (m & 7)) & 7);
      gl_lds16(&x[(size_t)(row0 + m) * 1024 + kb * 64 + g * 4],
               &xs[(it * 256 + t) * 4]);
    }
    // --- stage W tiles: straight contiguous copy (pre-swizzled) ---
    size_t tb = (size_t)(z * 16 + kb) * 2 * 4096;
#pragma unroll
    for (int it = 0; it < 2; ++it) {
      int off = (it * 256 + t) * 8; // shorts
      gl_lds16(&wsz[tb + off], &whs[off]);
    }
    if (split) {
#pragma unroll
      for (int it = 0; it < 2; ++it) {
        int off = (it * 256 + t) * 8;
        gl_lds16(&wsz[tb + 4096 + off], &wls[off]);
      }
    }
    __syncthreads();
    // --- compute: wave = 16 rows x 64 cols ---
    int m = wv * 16 + c;
#pragma unroll
    for (int kc = 0; kc < 2; ++kc) {
      s16x8 ah, al;
#pragma unroll
      for (int h = 0; h < 2; ++h) {
        int g = kc * 8 + quad * 2 + h;
        int p = (g & 8) | ((g ^ (c & 7)) & 7);
        f32x4 xv4 = *(const f32x4*)&xs[m * 64 + p * 4];
#pragma unroll
        for (int j = 0; j < 4; ++j) {
          unsigned hh = f2bf_u(xv4[j]);
          ah[h * 4 + j] = (short)hh;
          al[h * 4 + j] = (short)f2bf_u(xv4[j] - bf2f(hh));
        }
      }
#pragma unroll
      for (int cs = 0; cs < 4; ++cs) {
        int d = cs * 16 + c;
        int gk = kc * 4 + quad;
        int widx = d * 64 + ((gk ^ (d & 7)) * 8);
        s16x8 bh = *(const s16x8*)&whs[widx];
        acc[cs] = __builtin_amdgcn_mfma_f32_16x16x32_bf16(ah, bh, acc[cs], 0, 0, 0);
        if (split) {
          s16x8 bl = *(const s16x8*)&wls[widx];
          acc[cs] = __builtin_amdgcn_mfma_f32_16x16x32_bf16(ah, bl, acc[cs], 0, 0, 0);
          acc[cs] = __builtin_amdgcn_mfma_f32_16x16x32_bf16(al, bh, acc[cs], 0, 0, 0);
        }
      }
    }
    __syncthreads();
  }
  // epilogue: C layout row = quad*4+r, col = cs*16+c
  if (split) {
#pragma unroll
    for (int cs = 0; cs < 4; ++cs)
#pragma unroll
      for (int r = 0; r < 4; ++r) {
        int row = row0 + wv * 16 + quad * 4 + r;
        float val = acc[cs][r];
        unsigned h = f2bf_u(val);
        unsigned l = f2bf_u(val - bf2f(h));
        qkp[(size_t)z * MROWS * 64 + (size_t)row * 64 + cs * 16 + c] =
            (int)(h | (l << 16));
      }
  } else {
    // per-wave LDS transpose bounce (intra-wave DS ordering, no barrier)
#pragma unroll
    for (int cs = 0; cs < 4; ++cs)
#pragma unroll
      for (int r = 0; r < 4; ++r)
        pv[wv][quad * 4 + r][cs * 16 + c] = (short)f2bf_u(acc[cs][r]);
    int rowg = (row0 >> 4) + wv; // 16-row group id
    int n = rowg >> 7;
    int sb = (rowg * 16) & 2047;
    s16x8 p0, p1;
#pragma unroll
    for (int j = 0; j < 8; ++j) {
      p0[j] = pv[wv][j][lane];
      p1[j] = pv[wv][8 + j][lane];
    }
    *(s16x8*)&vhp_t[((size_t)n * 64 + lane) * 2048 + sb] = p0;
    *(s16x8*)&vhp_t[((size_t)n * 64 + lane) * 2048 + sb + 8] = p1;
  }
}

// ---------------------------------------------------------------------------
// Kernel 3: barrier-free causal flash attention with split-K partials.
// All K/V tile loads hoisted to the top of each kt iteration (one latency
// batch, ~24 loads in flight); register cap 256 (launch_bounds 256,2).
// ---------------------------------------------------------------------------
__global__ __launch_bounds__(256, 2) void attn_kernel(
    const int* __restrict__ qkp, const short* __restrict__ vhp_t,
    float* __restrict__ po, float* __restrict__ pm, float* __restrict__ pl,
    int S) {
  __shared__ short pS[4][16][72];
  int t = threadIdx.x;
  int wv = t >> 6, lane = t & 63;
  int c = lane & 15, quad = lane >> 4;
  int w = blockIdx.x * 4 + wv;
  int qg = w & 1023;   // absolute 16-row group (includes batch)
  int split = w >> 10; // chunk id
  int n = qg >> 7;
  int qgl = qg & 127;      // batch-LOCAL 16-row group
  int nk = (qgl >> 2) + 1; // 64-wide k tiles in causal range
  int dk = qgl >> 2;       // diagonal tile index
  int k0 = (split * nk) / S, k1 = ((split + 1) * nk) / S;
  const int* qp = qkp;
  const int* kp = qkp + (size_t)MROWS * 64;

  // Q A-frags, hi/lo unpack (row = qg*16 + c)
  s16x8 qfh[2], qfl[2];
  size_t qbase = (size_t)(qg * 16 + c) * 64;
#pragma unroll
  for (int kc = 0; kc < 2; ++kc) {
    i32x4 v0 = *(const i32x4*)&qp[qbase + kc * 32 + quad * 8];
    i32x4 v1 = *(const i32x4*)&qp[qbase + kc * 32 + quad * 8 + 4];
#pragma unroll
    for (int j = 0; j < 4; ++j) {
      qfh[kc][j] = (short)(v0[j] & 0xffff);
      qfl[kc][j] = (short)(((unsigned)v0[j]) >> 16);
      qfh[kc][4 + j] = (short)(v1[j] & 0xffff);
      qfl[kc][4 + j] = (short)(((unsigned)v1[j]) >> 16);
    }
  }
  s16x8 ones;
#pragma unroll
  for (int j = 0; j < 8; ++j) ones[j] = (short)0x3F80; // bf16 1.0
  f32x4 o[4] = {};
  f32x4 lsum = {};
  float m_r[4];
#pragma unroll
  for (int r = 0; r < 4; ++r) m_r[r] = -INFINITY;

  for (int kt = k0; kt < k1; ++kt) {
    int s0 = kt * 64;
    // ---- hoist ALL tile loads: 16 K i32x4 + 8 V s16x8 in flight ----
    i32x4 kr[4][4]; // [ct][kc*2+half]
#pragma unroll
    for (int ct = 0; ct < 4; ++ct) {
      const int* krow = &kp[((size_t)n * 2048 + s0 + ct * 16 + c) * 64];
#pragma unroll
      for (int q2 = 0; q2 < 4; ++q2)
        kr[ct][q2] =
            *(const i32x4*)&krow[(q2 >> 1) * 32 + quad * 8 + (q2 & 1) * 4];
    }
    s16x8 vf[4][2];
#pragma unroll
    for (int dt = 0; dt < 4; ++dt)
#pragma unroll
      for (int kc2 = 0; kc2 < 2; ++kc2)
        vf[dt][kc2] = *(const s16x8*)&vhp_t[((size_t)n * 64 + dt * 16 + c) * 2048 +
                                            s0 + kc2 * 32 + quad * 8];
    // ---- S = Q K^T, split-bf16 (hh+hl+lh) ----
    f32x4 sa[4] = {};
#pragma unroll
    for (int ct = 0; ct < 4; ++ct) {
#pragma unroll
      for (int kc = 0; kc < 2; ++kc) {
        i32x4 p0 = kr[ct][kc * 2];
        i32x4 p1 = kr[ct][kc * 2 + 1];
        s16x8 bh, bl;
#pragma unroll
        for (int j = 0; j < 4; ++j) {
          bh[j] = (short)(p0[j] & 0xffff);
          bl[j] = (short)(((unsigned)p0[j]) >> 16);
          bh[4 + j] = (short)(p1[j] & 0xffff);
          bl[4 + j] = (short)(((unsigned)p1[j]) >> 16);
        }
        sa[ct] = __builtin_amdgcn_mfma_f32_16x16x32_bf16(qfh[kc], bh, sa[ct], 0, 0, 0);
        sa[ct] = __builtin_amdgcn_mfma_f32_16x16x32_bf16(qfh[kc], bl, sa[ct], 0, 0, 0);
        sa[ct] = __builtin_amdgcn_mfma_f32_16x16x32_bf16(qfl[kc], bh, sa[ct], 0, 0, 0);
      }
    }
    // scale (faithful bug: *sqrt(D)=8) + causal mask on diagonal tile
    // (batch-LOCAL q row — round-3 bugfix retained)
    float sv[4][4];
    bool diag = (kt == dk);
#pragma unroll
    for (int ct = 0; ct < 4; ++ct)
#pragma unroll
      for (int r = 0; r < 4; ++r) {
        float xsc = sa[ct][r] * 8.0f;
        if (diag) {
          int sg = s0 + ct * 16 + c;
          int qgr = qgl * 16 + quad * 4 + r;
          if (sg > qgr) xsc = -INFINITY;
        }
        sv[ct][r] = xsc;
      }
    // online softmax: max reduction only (l comes from ones-MFMA)
    float alpha[4];
#pragma unroll
    for (int r = 0; r < 4; ++r) {
      float mx = fmaxf(fmaxf(sv[0][r], sv[1][r]), fmaxf(sv[2][r], sv[3][r]));
#pragma unroll
      for (int off = 1; off < 16; off <<= 1) mx = fmaxf(mx, __shfl_xor(mx, off, 64));
      float mnew = fmaxf(m_r[r], mx);
      alpha[r] = exp2f((m_r[r] - mnew) * L2E);
      m_r[r] = mnew;
#pragma unroll
      for (int ct = 0; ct < 4; ++ct)
        sv[ct][r] = exp2f((sv[ct][r] - mnew) * L2E);
    }
#pragma unroll
    for (int dt = 0; dt < 4; ++dt)
#pragma unroll
      for (int r = 0; r < 4; ++r) o[dt][r] *= alpha[r];
#pragma unroll
    for (int r = 0; r < 4; ++r) lsum[r] *= alpha[r];
    // P: C-layout -> per-wave LDS -> A-layout (intra-wave, no barrier)
#pragma unroll
    for (int ct = 0; ct < 4; ++ct)
#pragma unroll
      for (int r = 0; r < 4; ++r)
        pS[wv][quad * 4 + r][ct * 16 + c] = (short)f2bf_u(sv[ct][r]);
    s16x8 pa[2];
#pragma unroll
    for (int kc2 = 0; kc2 < 2; ++kc2)
      pa[kc2] = *(const s16x8*)&pS[wv][c][kc2 * 32 + quad * 8];
    // l += row-sum(P) via ones-MFMA; O += P V
    lsum = __builtin_amdgcn_mfma_f32_16x16x32_bf16(pa[0], ones, lsum, 0, 0, 0);
    lsum = __builtin_amdgcn_mfma_f32_16x16x32_bf16(pa[1], ones, lsum, 0, 0, 0);
#pragma unroll
    for (int dt = 0; dt < 4; ++dt) {
      o[dt] = __builtin_amdgcn_mfma_f32_16x16x32_bf16(pa[0], vf[dt][0], o[dt], 0, 0, 0);
      o[dt] = __builtin_amdgcn_mfma_f32_16x16x32_bf16(pa[1], vf[dt][1], o[dt], 0, 0, 0);
    }
  }
  // store partials (empty chunks store zeros / -inf)
  int rb = qg * 16 + quad * 4;
#pragma unroll
  for (int dt = 0; dt < 4; ++dt)
#pragma unroll
    for (int r = 0; r < 4; ++r)
      po[((size_t)split * MROWS + rb + r) * 64 + dt * 16 + c] = o[dt][r];
  if (c == 0) {
#pragma unroll
    for (int r = 0; r < 4; ++r) {
      pm[(size_t)split * MROWS + rb + r] = m_r[r];
      pl[(size_t)split * MROWS + rb + r] = lsum[r];
    }
  }
}

// ---------------------------------------------------------------------------
// Kernel 4: merge split-K partials. 262144 threads, one f32x4 each.
// ---------------------------------------------------------------------------
__global__ __launch_bounds__(256) void combine_kernel(
    const float* __restrict__ po, const float* __restrict__ pm,
    const float* __restrict__ pl, float* __restrict__ outp, int S) {
  int id = blockIdx.x * 256 + threadIdx.x;
  int row = id >> 4;
  int c4 = (id & 15) * 4;
  float M = -INFINITY;
  for (int s = 0; s < S; ++s) M = fmaxf(M, pm[(size_t)s * MROWS + row]);
  float den = 0.0f;
  f32x4 acc = {};
  for (int s = 0; s < S; ++s) {
    float wgt = exp2f((pm[(size_t)s * MROWS + row] - M) * L2E);
    den += pl[(size_t)s * MROWS + row] * wgt;
    f32x4 pvv = *(const f32x4*)&po[((size_t)s * MROWS + row) * 64 + c4];
#pragma unroll
    for (int j = 0; j < 4; ++j) acc[j] += pvv[j] * wgt;
  }
  f32x4 res;
#pragma unroll
  for (int j = 0; j < 4; ++j) res[j] = acc[j] / den;
  *(f32x4*)&outp[(size_t)row * 64 + c4] = res;
}

// ---------------------------------------------------------------------------
extern "C" void kernel_launch(void* const* d_in, const int* in_sizes, int n_in,
                              void* d_out, int out_size, void* d_ws, size_t ws_size,
                              hipStream_t stream) {
  const float* q = (const float*)d_in[0];
  const float* k = (const float*)d_in[1];
  const float* v = (const float*)d_in[2];
  const float* Wq = (const float*)d_in[3];
  const float* Wk = (const float*)d_in[4];
  const float* Wv = (const float*)d_in[5];
  float* out = (float*)d_out;

  char* ws = (char*)d_ws;
  // wsz: 786432 B | qkp: 8388608 B | vhp_t: 2097152 B | po/pm/pl per split
  size_t base = 786432 + 8388608 + 2097152; // 11272192
  size_t po_sz = (size_t)MROWS * 64 * 4;    // 4 MiB per split
  size_t ml_sz = (size_t)MROWS * 4;         // 64 KiB per split
  size_t per_split = po_sz + 2 * ml_sz;
  int S = 1;
  if (ws_size >= base + 4 * per_split) S = 4;
  else if (ws_size >= base + 2 * per_split) S = 2;

  short* wsz = (short*)ws;
  int* qkp = (int*)(ws + 786432);
  short* vhp_t = (short*)(ws + 786432 + 8388608);
  float* po = (float*)(ws + base);
  float* pm = (float*)(ws + base + (size_t)S * po_sz);
  float* pl = (float*)(ws + base + (size_t)S * po_sz + (size_t)S * ml_sz);

  wsplit_kernel<<<dim3(16, 3), 256, 0, stream>>>(Wq, Wk, Wv, wsz);
  proj_kernel<<<dim3(256, 3), 256, 0, stream>>>(q, k, v, wsz, qkp, vhp_t);
  attn_kernel<<<dim3(256 * S), 256, 0, stream>>>(qkp, vhp_t, po, pm, pl, S);
  combine_kernel<<<dim3(1024), 256, 0, stream>>>(po, pm, pl, out, S);
}